// Round 5
// baseline (721.792 us; speedup 1.0000x reference)
//
#include <hip/hip_runtime.h>

typedef unsigned short u16;
typedef unsigned int u32;
typedef __attribute__((ext_vector_type(8))) short short8;
typedef __attribute__((ext_vector_type(4))) float f32x4;

// ---------- bf16 helpers ----------
__device__ inline u16 f2b(float f) {  // RNE
  u32 u = __builtin_bit_cast(u32, f);
  u += 0x7fff + ((u >> 16) & 1);
  return (u16)(u >> 16);
}
__device__ inline float b2f(u16 u) {
  return __builtin_bit_cast(float, (u32)u << 16);
}
// round-to-nearest (ties away) pack — cheaper than RNE, used for P only
__device__ inline u32 pack_bf16_rn(float a, float b) {
  const u32 ua = __builtin_bit_cast(u32, a) + 0x8000u;
  const u32 ub = __builtin_bit_cast(u32, b) + 0x8000u;
  return (ua >> 16) | (ub & 0xffff0000u);
}
__device__ inline void c_store(float* p, float v) { *p = v; }
__device__ inline void c_store(u16* p, float v) { *p = f2b(v); }

__device__ inline float fexp2(float x) {
#if __has_builtin(__builtin_amdgcn_exp2f)
  return __builtin_amdgcn_exp2f(x);
#else
  return exp2f(x);
#endif
}

// ---------- async global->LDS, 16B per lane ----------
typedef const __attribute__((address_space(1))) u32 gu32;
typedef __attribute__((address_space(3))) u32 lu32;
__device__ inline void async16(const u16* g, u16* l) {
  __builtin_amdgcn_global_load_lds((gu32*)g, (lu32*)l, 16, 0, 0);
}

// Q scale folded into rmsnorm producer: 1/sqrt(128) * log2(e)
#define QS (0.08838834764831843f * 1.4426950408889634f)

// =====================================================================
// (32*MI)x128x(K,BK=32) bf16 GEMM, m97 structure. MI=4: 128-row tile
// (verified rounds 3-4). MI=2: 64-row tile for small-M / small-N shapes
// (2x the blocks for occupancy-starved dispatches).
// =====================================================================
template <int MI, typename TC>
__global__ __launch_bounds__(256) void gemm128_kernel(
    const u16* __restrict__ A, long lda,
    const u16* __restrict__ Bt, long ldb,
    TC* __restrict__ C0, TC* __restrict__ C1, TC* __restrict__ C2, long ldc,
    const float* b0, const float* b1, const float* b2,
    int K) {
  __shared__ u16 As[32 * MI * 32];
  __shared__ u16 Bs[128 * 32];

  const int tid = threadIdx.x;
  const int lane = tid & 63;
  const int w = tid >> 6;
  const int r = lane & 15;
  const int quad = lane >> 4;
  const int m0 = blockIdx.y * (32 * MI);
  const int nb = blockIdx.x * 128;
  const int seg = nb / 1536;
  const int nc = nb - seg * 1536;
  TC* C = seg == 0 ? C0 : (seg == 1 ? C1 : C2);
  const float* bias = seg == 0 ? b0 : (seg == 1 ? b1 : b2);

  const int srow = lane >> 2;
  const int sx = ((lane & 3) ^ (srow & 3)) * 8;
  const u16* Ag = A + (size_t)(m0 + w * 8 * MI + srow) * lda + sx;
  const u16* Bg = Bt + (size_t)(nb + w * 32 + srow) * ldb + sx;
  u16* Al[MI / 2];
#pragma unroll
  for (int j = 0; j < MI / 2; ++j) Al[j] = &As[(w * 8 * MI + 16 * j) * 32];
  u16* const Bl0 = &Bs[(w * 32) * 32];
  u16* const Bl1 = &Bs[(w * 32 + 16) * 32];

  const int wm = (w >> 1) * (16 * MI);
  const int wn = (w & 1) * 64;

  f32x4 acc[MI][4];
#pragma unroll
  for (int i = 0; i < MI; ++i)
#pragma unroll
    for (int j = 0; j < 4; ++j) acc[i][j] = (f32x4){0.f, 0.f, 0.f, 0.f};

  const int fco = (quad ^ (r & 3)) * 8;

  for (int kk = 0; kk < K; kk += 32) {
    __syncthreads();
#pragma unroll
    for (int j = 0; j < MI / 2; ++j) async16(Ag + kk + (size_t)(16 * j) * lda, Al[j]);
    async16(Bg + kk, Bl0);
    async16(Bg + kk + 16 * ldb, Bl1);
    __syncthreads();

    short8 af[MI], bf[4];
#pragma unroll
    for (int mi = 0; mi < MI; ++mi)
      af[mi] = *reinterpret_cast<const short8*>(&As[(wm + 16 * mi + r) * 32 + fco]);
#pragma unroll
    for (int ni = 0; ni < 4; ++ni)
      bf[ni] = *reinterpret_cast<const short8*>(&Bs[(wn + 16 * ni + r) * 32 + fco]);
#pragma unroll
    for (int mi = 0; mi < MI; ++mi)
#pragma unroll
      for (int ni = 0; ni < 4; ++ni)
        acc[mi][ni] = __builtin_amdgcn_mfma_f32_16x16x32_bf16(af[mi], bf[ni], acc[mi][ni], 0, 0, 0);
  }

#pragma unroll
  for (int mi = 0; mi < MI; ++mi)
#pragma unroll
    for (int ni = 0; ni < 4; ++ni)
#pragma unroll
      for (int rr = 0; rr < 4; ++rr) {
        const int row = m0 + wm + 16 * mi + 4 * quad + rr;
        const int col = nc + wn + 16 * ni + r;
        c_store(&C[(size_t)row * ldc + col], acc[mi][ni][rr] + bias[col]);
      }
}

// =====================================================================
// Merged f32->bf16 convert for hs and rhs
// =====================================================================
__global__ __launch_bounds__(256) void conv2_kernel(
    const float* __restrict__ xa, u16* __restrict__ ya, int n8a,
    const float* __restrict__ xb, u16* __restrict__ yb, int n8b) {
  int i = blockIdx.x * 256 + threadIdx.x;
  const float* x;
  u16* y;
  if (i < n8a) {
    x = xa; y = ya;
  } else {
    i -= n8a;
    if (i >= n8b) return;
    x = xb; y = yb;
  }
  const float4 v0 = reinterpret_cast<const float4*>(x)[2 * i];
  const float4 v1 = reinterpret_cast<const float4*>(x)[2 * i + 1];
  uint4 rv;
  rv.x = (u32)f2b(v0.x) | ((u32)f2b(v0.y) << 16);
  rv.y = (u32)f2b(v0.z) | ((u32)f2b(v0.w) << 16);
  rv.z = (u32)f2b(v1.x) | ((u32)f2b(v1.y) << 16);
  rv.w = (u32)f2b(v1.z) | ((u32)f2b(v1.w) << 16);
  reinterpret_cast<uint4*>(y)[i] = rv;
}

// =====================================================================
// Transpose-convert (W f32 [1536][1536] -> Wt bf16 transposed)
// =====================================================================
__device__ inline void transconv_body(const float* __restrict__ W, u16* __restrict__ Wt) {
  __shared__ u16 Ls[64 * 72];
  const int tid = threadIdx.x;
  const int k0 = blockIdx.y * 64;
  const int n0 = blockIdx.x * 64;
#pragma unroll
  for (int i = 0; i < 4; ++i) {
    const int c = tid + 256 * i;
    const int row = c >> 4;
    const int c4 = (c & 15) * 4;
    const float4 v = *reinterpret_cast<const float4*>(&W[(size_t)(k0 + row) * 1536 + n0 + c4]);
    Ls[(c4 + 0) * 72 + row] = f2b(v.x);
    Ls[(c4 + 1) * 72 + row] = f2b(v.y);
    Ls[(c4 + 2) * 72 + row] = f2b(v.z);
    Ls[(c4 + 3) * 72 + row] = f2b(v.w);
  }
  __syncthreads();
#pragma unroll
  for (int i = 0; i < 2; ++i) {
    const int c = tid + 256 * i;
    const int n = c >> 3;
    const int kc = (c & 7) * 8;
    u16 tmp[8];
#pragma unroll
    for (int j = 0; j < 8; ++j) tmp[j] = Ls[n * 72 + kc + j];
    *reinterpret_cast<uint4*>(&Wt[(size_t)(n0 + n) * 1536 + k0 + kc]) =
        *reinterpret_cast<const uint4*>(tmp);
  }
}

__global__ __launch_bounds__(256) void transconv5_kernel(
    const float* W0, const float* W1, const float* W2, const float* W3, const float* W4,
    u16* T0, u16* T1, u16* T2, u16* T3, u16* T4) {
  const int z = blockIdx.z;
  const float* W = z == 0 ? W0 : z == 1 ? W1 : z == 2 ? W2 : z == 3 ? W3 : W4;
  u16* Wt = z == 0 ? T0 : z == 1 ? T1 : z == 2 ? T2 : z == 3 ? T3 : T4;
  transconv_body(W, Wt);
}

__global__ __launch_bounds__(256) void transconv_kernel(
    const float* __restrict__ W, u16* __restrict__ Wt) {
  transconv_body(W, Wt);
}

// =====================================================================
// Merged RMSNorm: z=0 q-path (scaled by QS, plain+rope), z=1 k-path
// (rope), z=2 ref-k (1024 rows, plain). Verified round 4.
// =====================================================================
__global__ __launch_bounds__(256) void rmsnorm3_kernel(
    const u16* xq, const u16* xk, const u16* xkr,
    const float* gq, const float* gk,
    const float* rc, const float* rs,
    u16* oq_plain, u16* oq_rope, u16* ok_rope, u16* okr_plain) {
  __shared__ float red[4];
  const int z = blockIdx.y;
  const int row = blockIdx.x;
  if (z == 2 && row >= 1024) return;
  const u16* x; const float* g; u16* po; u16* pr; float sc;
  if (z == 0)      { x = xq;  g = gq; po = oq_plain; pr = oq_rope; sc = QS;  }
  else if (z == 1) { x = xk;  g = gk; po = nullptr;  pr = ok_rope; sc = 1.f; }
  else             { x = xkr; g = gk; po = okr_plain; pr = nullptr; sc = 1.f; }

  const int tid = threadIdx.x;
  const u32* xr = reinterpret_cast<const u32*>(x + (size_t)row * 1536);
  float xe[3], xo[3];
  float ss = 0.f;
#pragma unroll
  for (int j = 0; j < 3; ++j) {
    const u32 u = xr[tid + 256 * j];
    const float e = b2f((u16)(u & 0xffff));
    const float o = b2f((u16)(u >> 16));
    xe[j] = e; xo[j] = o;
    ss += e * e + o * o;
  }
#pragma unroll
  for (int off = 32; off; off >>= 1) ss += __shfl_xor(ss, off, 64);
  if ((tid & 63) == 0) red[tid >> 6] = ss;
  __syncthreads();
  const float total = red[0] + red[1] + red[2] + red[3];
  const float rinv = rsqrtf(total * (1.0f / 1536.0f) + 1e-6f) * sc;
  u32* po32 = po ? reinterpret_cast<u32*>(po + (size_t)row * 1536) : nullptr;
  u32* pr32 = pr ? reinterpret_cast<u32*>(pr + (size_t)row * 1536) : nullptr;
#pragma unroll
  for (int j = 0; j < 3; ++j) {
    const int p = tid + 256 * j;
    const float2 gg = reinterpret_cast<const float2*>(g)[p];
    const float e = xe[j] * rinv * gg.x;
    const float o = xo[j] * rinv * gg.y;
    if (po32) po32[p] = (u32)f2b(e) | ((u32)f2b(o) << 16);
    if (pr32) {
      const int i = p & 63;
      const float c = rc[row * 64 + i];
      const float s = rs[row * 64 + i];
      const float re = e * c - o * s;
      const float im = e * s + o * c;
      pr32[p] = (u32)f2b(re) | ((u32)f2b(im) << 16);
    }
  }
}

// =====================================================================
// Merged per-head V transpose (verified round 4)
// =====================================================================
__global__ __launch_bounds__(256) void vtrans2_kernel(
    const u16* __restrict__ V0, u16* __restrict__ Vt0,
    const u16* __restrict__ V1, u16* __restrict__ Vt1) {
  __shared__ u16 Ls[64 * 136];
  const int z = blockIdx.z;
  const int kvLen = z == 0 ? 4096 : 1024;
  const int kv0 = blockIdx.x * 64;
  if (kv0 >= kvLen) return;
  const u16* V = z == 0 ? V0 : V1;
  u16* Vt = z == 0 ? Vt0 : Vt1;
  const int tid = threadIdx.x;
  const int h = blockIdx.y;
#pragma unroll
  for (int i = 0; i < 4; ++i) {
    const int c = tid + 256 * i;
    const int row = c >> 4, c8 = c & 15;
    *reinterpret_cast<uint4*>(&Ls[row * 136 + 8 * c8]) =
        *reinterpret_cast<const uint4*>(V + (size_t)(kv0 + row) * 1536 + h * 128 + 8 * c8);
  }
  __syncthreads();
#pragma unroll
  for (int i = 0; i < 4; ++i) {
    const int c = tid + 256 * i;
    const int d = c >> 3, kc = c & 7;
    u16 tmp[8];
#pragma unroll
    for (int j = 0; j < 8; ++j) tmp[j] = Ls[(8 * kc + j) * 136 + d];
    *reinterpret_cast<uint4*>(Vt + ((size_t)h * 128 + d) * kvLen + kv0 + 8 * kc) =
        *reinterpret_cast<const uint4*>(tmp);
  }
}

// =====================================================================
// Fused dual flash attention (cross then main per block), double-buffered
// single-barrier K/V staging via global_load_lds.
//   Phase 0: Q=Qc (prescaled rmsnorm q), K/V = ref (kv=1024) -> Ox regs
//   Phase 1: Q=Qm (roped), K/V = main (kv=4096); out = Omain + Ox -> bf16 Ob
// Pipeline: sync -> issue DMA(t+1, buf^1) -> compute(t, buf). The barrier's
// vmcnt(0) drain waits on a DMA issued one full tile earlier (overlapped);
// DMA-issue sits AFTER the barrier so the drain never covers the fresh tile.
// Swizzles / fragment mappings identical to verified round 4.
// =====================================================================
__global__ __launch_bounds__(256) void flash2_kernel(
    const u16* __restrict__ Qc, const u16* __restrict__ Kc, const u16* __restrict__ Vtc,
    const u16* __restrict__ Qm, const u16* __restrict__ Km, const u16* __restrict__ Vtm,
    u16* __restrict__ Ob) {
  __shared__ u16 Ks[2][64 * 128];
  __shared__ u16 Vs[2][128 * 64];
  __shared__ u16 Pb[4][16 * 72];
  __shared__ float ab[4][16];

  const int tid = threadIdx.x;
  const int lane = tid & 63;
  const int w = tid >> 6;
  const int r = lane & 15;
  const int quad = lane >> 4;
  const int h = blockIdx.y;
  const int q0 = blockIdx.x * 64;
  const int qrow = q0 + 16 * w + r;
  const int sw = r & 7;

  f32x4 Ox[8];
#pragma unroll
  for (int dt = 0; dt < 8; ++dt) Ox[dt] = (f32x4){0.f, 0.f, 0.f, 0.f};

  for (int ph = 0; ph < 2; ++ph) {
    const u16* Q  = ph ? Qm : Qc;
    const u16* K  = ph ? Km : Kc;
    const u16* Vt = ph ? Vtm : Vtc;
    const int kvLen = ph ? 4096 : 1024;
    const int nt = kvLen >> 6;

    // Q fragments (B-operand of S^T): lane holds Q[qrow][32ks+8quad+j]
    short8 qf[4];
    {
      const u16* qbase = Q + (size_t)qrow * 1536 + h * 128 + 8 * quad;
#pragma unroll
      for (int ks = 0; ks < 4; ++ks)
        qf[ks] = *reinterpret_cast<const short8*>(qbase + 32 * ks);
    }

    // staging pointers (swizzle folded into global lane order)
    const u16* Vth = Vt + (size_t)h * 128 * kvLen;
    const u16* kg[4]; const u16* vg[4];
    int klo[4], vlo[4];
    {
      const int p16 = lane & 15, rin = lane >> 4;
      const int p8 = lane & 7, din = lane >> 3;
#pragma unroll
      for (int j = 0; j < 4; ++j) {
        const int row = 16 * w + 4 * j + rin;
        kg[j] = K + (size_t)row * 1536 + h * 128 + 8 * (p16 ^ (row & 15));
        klo[j] = (16 * w + 4 * j) * 128;
        const int d = 32 * w + 8 * j + din;
        vg[j] = Vth + (size_t)d * kvLen + 8 * (p8 ^ (d & 7));
        vlo[j] = (32 * w + 8 * j) * 64;
      }
    }

    f32x4 Oc[8];
#pragma unroll
    for (int dt = 0; dt < 8; ++dt) Oc[dt] = (f32x4){0.f, 0.f, 0.f, 0.f};
    float m_i = -1e30f, l_i = 0.f;

    __syncthreads();  // buffers free (cross-phase reuse)
#pragma unroll
    for (int j = 0; j < 4; ++j) async16(kg[j], &Ks[0][klo[j]]);
#pragma unroll
    for (int j = 0; j < 4; ++j) async16(vg[j], &Vs[0][vlo[j]]);

    int buf = 0;
    for (int t = 0; t < nt; ++t) {
      __syncthreads();  // drains my tile-t DMA (issued one tile ago)
      if (t + 1 < nt) {
        const size_t ko = (size_t)(t + 1) * 64 * 1536;
        const int vo = (t + 1) * 64;
#pragma unroll
        for (int j = 0; j < 4; ++j) async16(kg[j] + ko, &Ks[buf ^ 1][klo[j]]);
#pragma unroll
        for (int j = 0; j < 4; ++j) async16(vg[j] + vo, &Vs[buf ^ 1][vlo[j]]);
      }
      const u16* Ksb = Ks[buf];
      const u16* Vsb = Vs[buf];

      // S^T = K * Q^T (log2-domain; Q pre-scaled)
      f32x4 St[4];
#pragma unroll
      for (int mt = 0; mt < 4; ++mt) St[mt] = (f32x4){0.f, 0.f, 0.f, 0.f};
#pragma unroll
      for (int mt = 0; mt < 4; ++mt) {
        const u16* kp = &Ksb[(16 * mt + r) * 128];
#pragma unroll
        for (int ks = 0; ks < 4; ++ks) {
          const short8 af = *reinterpret_cast<const short8*>(kp + 8 * ((quad + 4 * ks) ^ r));
          St[mt] = __builtin_amdgcn_mfma_f32_16x16x32_bf16(af, qf[ks], St[mt], 0, 0, 0);
        }
      }

      // online softmax (base 2); lane owns q-row r
      float mloc = -1e30f;
#pragma unroll
      for (int mt = 0; mt < 4; ++mt)
#pragma unroll
        for (int rr = 0; rr < 4; ++rr) mloc = fmaxf(mloc, St[mt][rr]);
      mloc = fmaxf(mloc, __shfl_xor(mloc, 16, 64));
      mloc = fmaxf(mloc, __shfl_xor(mloc, 32, 64));
      const float mn = fmaxf(m_i, mloc);

      float alpha = 1.0f;
      if (__any(mloc > m_i)) {
        alpha = fexp2(m_i - mn);
        if (quad == 0) ab[w][r] = alpha;
        const float4 a4 = *reinterpret_cast<const float4*>(&ab[w][4 * quad]);
#pragma unroll
        for (int dt = 0; dt < 8; ++dt) {
          Oc[dt][0] *= a4.x; Oc[dt][1] *= a4.y; Oc[dt][2] *= a4.z; Oc[dt][3] *= a4.w;
        }
      }

      float psum = 0.f;
      uint2 pk[4];
#pragma unroll
      for (int mt = 0; mt < 4; ++mt) {
        const float p0 = fexp2(St[mt][0] - mn);
        const float p1 = fexp2(St[mt][1] - mn);
        const float p2 = fexp2(St[mt][2] - mn);
        const float p3 = fexp2(St[mt][3] - mn);
        psum += (p0 + p1) + (p2 + p3);
        pk[mt].x = pack_bf16_rn(p0, p1);
        pk[mt].y = pack_bf16_rn(p2, p3);
      }
      psum += __shfl_xor(psum, 16, 64);
      psum += __shfl_xor(psum, 32, 64);
      l_i = l_i * alpha + psum;
      m_i = mn;

      // P -> wave-private LDS (A-operand layout [q=r][kpos])
#pragma unroll
      for (int mt = 0; mt < 4; ++mt)
        *reinterpret_cast<uint2*>(&Pb[w][r * 72 + 16 * mt + 4 * quad]) = pk[mt];

      const short8 pa0 = *reinterpret_cast<const short8*>(&Pb[w][r * 72 + 8 * quad]);
      const short8 pa1 = *reinterpret_cast<const short8*>(&Pb[w][r * 72 + 32 + 8 * quad]);

      // O += P * V
#pragma unroll
      for (int dt = 0; dt < 8; ++dt) {
        const int d = 16 * dt + r;
        const short8 b0 = *reinterpret_cast<const short8*>(&Vsb[d * 64 + 8 * (quad ^ sw)]);
        const short8 b1 = *reinterpret_cast<const short8*>(&Vsb[d * 64 + 8 * ((4 + quad) ^ sw)]);
        Oc[dt] = __builtin_amdgcn_mfma_f32_16x16x32_bf16(pa0, b0, Oc[dt], 0, 0, 0);
        Oc[dt] = __builtin_amdgcn_mfma_f32_16x16x32_bf16(pa1, b1, Oc[dt], 0, 0, 0);
      }
      buf ^= 1;
    }

    // phase finalize: normalize by 1/l (LDS broadcast, wave-private)
    if (quad == 0) ab[w][r] = 1.0f / l_i;
    const float4 li4 = *reinterpret_cast<const float4*>(&ab[w][4 * quad]);
    const float lv[4] = {li4.x, li4.y, li4.z, li4.w};
    if (ph == 0) {
#pragma unroll
      for (int dt = 0; dt < 8; ++dt)
#pragma unroll
        for (int rr = 0; rr < 4; ++rr) Ox[dt][rr] = Oc[dt][rr] * lv[rr];
    } else {
      u16* obb = Ob + (size_t)(q0 + 16 * w) * 1536 + h * 128;
#pragma unroll
      for (int rr = 0; rr < 4; ++rr) {
        u16* brow = obb + (size_t)(4 * quad + rr) * 1536 + r;
#pragma unroll
        for (int dt = 0; dt < 8; ++dt)
          brow[16 * dt] = f2b(Oc[dt][rr] * lv[rr] + Ox[dt][rr]);
      }
    }
  }
}

// =====================================================================
// Host orchestration (9 dispatches)
// =====================================================================
extern "C" void kernel_launch(void* const* d_in, const int* in_sizes, int n_in,
                              void* d_out, int out_size, void* d_ws, size_t ws_size,
                              hipStream_t stream) {
  (void)in_sizes; (void)n_in; (void)out_size; (void)ws_size;
  constexpr int T = 4096, TR = 1024, DIM = 1536, NH = 12;

  const float* hs  = (const float*)d_in[0];
  const float* rhs = (const float*)d_in[1];
  const float* rc  = (const float*)d_in[2];
  const float* rs  = (const float*)d_in[3];
  const float* Wq  = (const float*)d_in[4];
  const float* bq  = (const float*)d_in[5];
  const float* Wk  = (const float*)d_in[6];
  const float* bk  = (const float*)d_in[7];
  const float* Wv  = (const float*)d_in[8];
  const float* bv  = (const float*)d_in[9];
  const float* Wkr = (const float*)d_in[10];
  const float* bkr = (const float*)d_in[11];
  const float* Wvr = (const float*)d_in[12];
  const float* bvr = (const float*)d_in[13];
  const float* Wo  = (const float*)d_in[14];
  const float* bo  = (const float*)d_in[15];
  const float* gq  = (const float*)d_in[16];
  const float* gk  = (const float*)d_in[17];
  float* out = (float*)d_out;

  char* ws = (char*)d_ws;
  size_t off = 0;
  auto alloc = [&](size_t bytes) -> void* {
    void* p = ws + off;
    off += (bytes + 255) & ~(size_t)255;
    return p;
  };
  u16* bQ    = (u16*)alloc((size_t)T * DIM * 2);
  u16* bQr   = (u16*)alloc((size_t)T * DIM * 2);
  u16* bK    = (u16*)alloc((size_t)T * DIM * 2);
  u16* bV    = (u16*)alloc((size_t)T * DIM * 2);
  u16* bKr   = (u16*)alloc((size_t)TR * DIM * 2);
  u16* bVr   = (u16*)alloc((size_t)TR * DIM * 2);
  u16* bHs   = (u16*)alloc((size_t)T * DIM * 2);       // bf16 hs; ALIAS-> VtG
  u16* bRhs  = (u16*)alloc((size_t)TR * DIM * 2);      // bf16 rhs; ALIAS-> VtR
  u16* bWqkv = (u16*)alloc((size_t)3 * DIM * DIM * 2); // WqT|WkT|WvT; ALIAS-> bOb
  u16* bWr   = (u16*)alloc((size_t)2 * DIM * DIM * 2); // WkrT|WvrT; ALIAS-> bWoT
  u16* VtG = bHs;
  u16* VtR = bRhs;
  u16* bOb = bWqkv;
  u16* bWoT = bWr;

  const dim3 blk(256);

  // 1. f32->bf16 converts (merged)
  conv2_kernel<<<dim3((T * DIM / 8 + TR * DIM / 8 + 255) / 256), blk, 0, stream>>>(
      hs, bHs, T * DIM / 8, rhs, bRhs, TR * DIM / 8);

  // 2. weight transpose-converts (Wq,Wk,Wv,Wkr,Wvr merged)
  transconv5_kernel<<<dim3(24, 24, 5), blk, 0, stream>>>(
      Wq, Wk, Wv, Wkr, Wvr,
      bWqkv + 0 * (size_t)DIM * DIM, bWqkv + 1 * (size_t)DIM * DIM,
      bWqkv + 2 * (size_t)DIM * DIM, bWr + 0 * (size_t)DIM * DIM,
      bWr + 1 * (size_t)DIM * DIM);

  // 3-4. projections (QKV fused 128-tile; KrVr 64-tile for occupancy)
  gemm128_kernel<4, u16><<<dim3(36, 32), blk, 0, stream>>>(
      bHs, DIM, bWqkv, DIM, bQ, bK, bV, DIM, bq, bk, bv, DIM);
  gemm128_kernel<2, u16><<<dim3(24, 16), blk, 0, stream>>>(
      bRhs, DIM, bWr, DIM, bKr, bVr, (u16*)nullptr, DIM, bkr, bvr, nullptr, DIM);

  // 5. Wo transpose AFTER KrVr gemm (bWoT aliases bWr)
  transconv_kernel<<<dim3(24, 24), blk, 0, stream>>>(Wo, bWoT);

  // 6. rmsnorm/rope (merged; q-path pre-scaled by QS)
  rmsnorm3_kernel<<<dim3(T, 3), blk, 0, stream>>>(
      bQ, bK, bKr, gq, gk, rc, rs, bQ, bQr, bK, bKr);

  // 7. per-head V transposes (merged; alias buffers are dead)
  vtrans2_kernel<<<dim3(T / 64, NH, 2), blk, 0, stream>>>(bV, VtG, bVr, VtR);

  // 8. fused dual flash attention -> bf16 bOb
  flash2_kernel<<<dim3(T / 64, NH), blk, 0, stream>>>(
      bQ, bKr, VtR, bQr, bK, VtG, bOb);

  // 9. output projection (64-row tiles for occupancy)
  gemm128_kernel<2, float><<<dim3(12, 64), blk, 0, stream>>>(
      bOb, DIM, bWoT, DIM, out, (float*)nullptr, (float*)nullptr, DIM, bo, nullptr, nullptr, DIM);
}

// Round 6
// 604.465 us; speedup vs baseline: 1.1941x; 1.1941x over previous
//
#include <hip/hip_runtime.h>

typedef unsigned short u16;
typedef unsigned int u32;
typedef __attribute__((ext_vector_type(8))) short short8;
typedef __attribute__((ext_vector_type(4))) float f32x4;

// ---------- bf16 helpers ----------
__device__ inline u16 f2b(float f) {  // RNE
  u32 u = __builtin_bit_cast(u32, f);
  u += 0x7fff + ((u >> 16) & 1);
  return (u16)(u >> 16);
}
__device__ inline float b2f(u16 u) {
  return __builtin_bit_cast(float, (u32)u << 16);
}
// round-to-nearest (ties away) pack — cheaper than RNE, used for P only
__device__ inline u32 pack_bf16_rn(float a, float b) {
  const u32 ua = __builtin_bit_cast(u32, a) + 0x8000u;
  const u32 ub = __builtin_bit_cast(u32, b) + 0x8000u;
  return (ua >> 16) | (ub & 0xffff0000u);
}
__device__ inline void c_store(float* p, float v) { *p = v; }
__device__ inline void c_store(u16* p, float v) { *p = f2b(v); }

__device__ inline float fexp2(float x) {
#if __has_builtin(__builtin_amdgcn_exp2f)
  return __builtin_amdgcn_exp2f(x);
#else
  return exp2f(x);
#endif
}

// ---------- async global->LDS, 16B per lane ----------
typedef const __attribute__((address_space(1))) u32 gu32;
typedef __attribute__((address_space(3))) u32 lu32;
__device__ inline void async16(const u16* g, u16* l) {
  __builtin_amdgcn_global_load_lds((gu32*)g, (lu32*)l, 16, 0, 0);
}

// Q scale folded into rmsnorm producer: 1/sqrt(128) * log2(e)
#define QS (0.08838834764831843f * 1.4426950408889634f)

// =====================================================================
// (32*MI)x128x(K,BK=32) bf16 GEMM, m97 structure (verified r3-r5).
// MI=4: 128-row tile. MI=2: 64-row tile for occupancy-starved shapes.
// =====================================================================
template <int MI, typename TC>
__global__ __launch_bounds__(256) void gemm128_kernel(
    const u16* __restrict__ A, long lda,
    const u16* __restrict__ Bt, long ldb,
    TC* __restrict__ C0, TC* __restrict__ C1, TC* __restrict__ C2, long ldc,
    const float* b0, const float* b1, const float* b2,
    int K) {
  __shared__ u16 As[32 * MI * 32];
  __shared__ u16 Bs[128 * 32];

  const int tid = threadIdx.x;
  const int lane = tid & 63;
  const int w = tid >> 6;
  const int r = lane & 15;
  const int quad = lane >> 4;
  const int m0 = blockIdx.y * (32 * MI);
  const int nb = blockIdx.x * 128;
  const int seg = nb / 1536;
  const int nc = nb - seg * 1536;
  TC* C = seg == 0 ? C0 : (seg == 1 ? C1 : C2);
  const float* bias = seg == 0 ? b0 : (seg == 1 ? b1 : b2);

  const int srow = lane >> 2;
  const int sx = ((lane & 3) ^ (srow & 3)) * 8;
  const u16* Ag = A + (size_t)(m0 + w * 8 * MI + srow) * lda + sx;
  const u16* Bg = Bt + (size_t)(nb + w * 32 + srow) * ldb + sx;
  u16* Al[MI / 2];
#pragma unroll
  for (int j = 0; j < MI / 2; ++j) Al[j] = &As[(w * 8 * MI + 16 * j) * 32];
  u16* const Bl0 = &Bs[(w * 32) * 32];
  u16* const Bl1 = &Bs[(w * 32 + 16) * 32];

  const int wm = (w >> 1) * (16 * MI);
  const int wn = (w & 1) * 64;

  f32x4 acc[MI][4];
#pragma unroll
  for (int i = 0; i < MI; ++i)
#pragma unroll
    for (int j = 0; j < 4; ++j) acc[i][j] = (f32x4){0.f, 0.f, 0.f, 0.f};

  const int fco = (quad ^ (r & 3)) * 8;

  for (int kk = 0; kk < K; kk += 32) {
    __syncthreads();
#pragma unroll
    for (int j = 0; j < MI / 2; ++j) async16(Ag + kk + (size_t)(16 * j) * lda, Al[j]);
    async16(Bg + kk, Bl0);
    async16(Bg + kk + 16 * ldb, Bl1);
    __syncthreads();

    short8 af[MI], bf[4];
#pragma unroll
    for (int mi = 0; mi < MI; ++mi)
      af[mi] = *reinterpret_cast<const short8*>(&As[(wm + 16 * mi + r) * 32 + fco]);
#pragma unroll
    for (int ni = 0; ni < 4; ++ni)
      bf[ni] = *reinterpret_cast<const short8*>(&Bs[(wn + 16 * ni + r) * 32 + fco]);
#pragma unroll
    for (int mi = 0; mi < MI; ++mi)
#pragma unroll
      for (int ni = 0; ni < 4; ++ni)
        acc[mi][ni] = __builtin_amdgcn_mfma_f32_16x16x32_bf16(af[mi], bf[ni], acc[mi][ni], 0, 0, 0);
  }

#pragma unroll
  for (int mi = 0; mi < MI; ++mi)
#pragma unroll
    for (int ni = 0; ni < 4; ++ni)
#pragma unroll
      for (int rr = 0; rr < 4; ++rr) {
        const int row = m0 + wm + 16 * mi + 4 * quad + rr;
        const int col = nc + wn + 16 * ni + r;
        c_store(&C[(size_t)row * ldc + col], acc[mi][ni][rr] + bias[col]);
      }
}

// =====================================================================
// Merged f32->bf16 convert for hs and rhs
// =====================================================================
__global__ __launch_bounds__(256) void conv2_kernel(
    const float* __restrict__ xa, u16* __restrict__ ya, int n8a,
    const float* __restrict__ xb, u16* __restrict__ yb, int n8b) {
  int i = blockIdx.x * 256 + threadIdx.x;
  const float* x;
  u16* y;
  if (i < n8a) {
    x = xa; y = ya;
  } else {
    i -= n8a;
    if (i >= n8b) return;
    x = xb; y = yb;
  }
  const float4 v0 = reinterpret_cast<const float4*>(x)[2 * i];
  const float4 v1 = reinterpret_cast<const float4*>(x)[2 * i + 1];
  uint4 rv;
  rv.x = (u32)f2b(v0.x) | ((u32)f2b(v0.y) << 16);
  rv.y = (u32)f2b(v0.z) | ((u32)f2b(v0.w) << 16);
  rv.z = (u32)f2b(v1.x) | ((u32)f2b(v1.y) << 16);
  rv.w = (u32)f2b(v1.z) | ((u32)f2b(v1.w) << 16);
  reinterpret_cast<uint4*>(y)[i] = rv;
}

// =====================================================================
// Transpose-convert, all 6 weights merged (W f32 [1536][1536] -> Wt^T bf16)
// =====================================================================
__device__ inline void transconv_body(const float* __restrict__ W, u16* __restrict__ Wt) {
  __shared__ u16 Ls[64 * 72];
  const int tid = threadIdx.x;
  const int k0 = blockIdx.y * 64;
  const int n0 = blockIdx.x * 64;
#pragma unroll
  for (int i = 0; i < 4; ++i) {
    const int c = tid + 256 * i;
    const int row = c >> 4;
    const int c4 = (c & 15) * 4;
    const float4 v = *reinterpret_cast<const float4*>(&W[(size_t)(k0 + row) * 1536 + n0 + c4]);
    Ls[(c4 + 0) * 72 + row] = f2b(v.x);
    Ls[(c4 + 1) * 72 + row] = f2b(v.y);
    Ls[(c4 + 2) * 72 + row] = f2b(v.z);
    Ls[(c4 + 3) * 72 + row] = f2b(v.w);
  }
  __syncthreads();
#pragma unroll
  for (int i = 0; i < 2; ++i) {
    const int c = tid + 256 * i;
    const int n = c >> 3;
    const int kc = (c & 7) * 8;
    u16 tmp[8];
#pragma unroll
    for (int j = 0; j < 8; ++j) tmp[j] = Ls[n * 72 + kc + j];
    *reinterpret_cast<uint4*>(&Wt[(size_t)(n0 + n) * 1536 + k0 + kc]) =
        *reinterpret_cast<const uint4*>(tmp);
  }
}

__global__ __launch_bounds__(256) void transconv6_kernel(
    const float* W0, const float* W1, const float* W2,
    const float* W3, const float* W4, const float* W5,
    u16* T0, u16* T1, u16* T2, u16* T3, u16* T4, u16* T5) {
  const int z = blockIdx.z;
  const float* W = z == 0 ? W0 : z == 1 ? W1 : z == 2 ? W2 : z == 3 ? W3 : z == 4 ? W4 : W5;
  u16* Wt = z == 0 ? T0 : z == 1 ? T1 : z == 2 ? T2 : z == 3 ? T3 : z == 4 ? T4 : T5;
  transconv_body(W, Wt);
}

// =====================================================================
// Merged RMSNorm: z=0 q-path (scaled by QS, plain+rope), z=1 k-path
// (rope), z=2 ref-k (1024 rows, plain). Verified r4-r5.
// =====================================================================
__global__ __launch_bounds__(256) void rmsnorm3_kernel(
    const u16* xq, const u16* xk, const u16* xkr,
    const float* gq, const float* gk,
    const float* rc, const float* rs,
    u16* oq_plain, u16* oq_rope, u16* ok_rope, u16* okr_plain) {
  __shared__ float red[4];
  const int z = blockIdx.y;
  const int row = blockIdx.x;
  if (z == 2 && row >= 1024) return;
  const u16* x; const float* g; u16* po; u16* pr; float sc;
  if (z == 0)      { x = xq;  g = gq; po = oq_plain; pr = oq_rope; sc = QS;  }
  else if (z == 1) { x = xk;  g = gk; po = nullptr;  pr = ok_rope; sc = 1.f; }
  else             { x = xkr; g = gk; po = okr_plain; pr = nullptr; sc = 1.f; }

  const int tid = threadIdx.x;
  const u32* xr = reinterpret_cast<const u32*>(x + (size_t)row * 1536);
  float xe[3], xo[3];
  float ss = 0.f;
#pragma unroll
  for (int j = 0; j < 3; ++j) {
    const u32 u = xr[tid + 256 * j];
    const float e = b2f((u16)(u & 0xffff));
    const float o = b2f((u16)(u >> 16));
    xe[j] = e; xo[j] = o;
    ss += e * e + o * o;
  }
#pragma unroll
  for (int off = 32; off; off >>= 1) ss += __shfl_xor(ss, off, 64);
  if ((tid & 63) == 0) red[tid >> 6] = ss;
  __syncthreads();
  const float total = red[0] + red[1] + red[2] + red[3];
  const float rinv = rsqrtf(total * (1.0f / 1536.0f) + 1e-6f) * sc;
  u32* po32 = po ? reinterpret_cast<u32*>(po + (size_t)row * 1536) : nullptr;
  u32* pr32 = pr ? reinterpret_cast<u32*>(pr + (size_t)row * 1536) : nullptr;
#pragma unroll
  for (int j = 0; j < 3; ++j) {
    const int p = tid + 256 * j;
    const float2 gg = reinterpret_cast<const float2*>(g)[p];
    const float e = xe[j] * rinv * gg.x;
    const float o = xo[j] * rinv * gg.y;
    if (po32) po32[p] = (u32)f2b(e) | ((u32)f2b(o) << 16);
    if (pr32) {
      const int i = p & 63;
      const float c = rc[row * 64 + i];
      const float s = rs[row * 64 + i];
      const float re = e * c - o * s;
      const float im = e * s + o * c;
      pr32[p] = (u32)f2b(re) | ((u32)f2b(im) << 16);
    }
  }
}

// =====================================================================
// Merged per-head V transpose (verified r4-r5)
// =====================================================================
__global__ __launch_bounds__(256) void vtrans2_kernel(
    const u16* __restrict__ V0, u16* __restrict__ Vt0,
    const u16* __restrict__ V1, u16* __restrict__ Vt1) {
  __shared__ u16 Ls[64 * 136];
  const int z = blockIdx.z;
  const int kvLen = z == 0 ? 4096 : 1024;
  const int kv0 = blockIdx.x * 64;
  if (kv0 >= kvLen) return;
  const u16* V = z == 0 ? V0 : V1;
  u16* Vt = z == 0 ? Vt0 : Vt1;
  const int tid = threadIdx.x;
  const int h = blockIdx.y;
#pragma unroll
  for (int i = 0; i < 4; ++i) {
    const int c = tid + 256 * i;
    const int row = c >> 4, c8 = c & 15;
    *reinterpret_cast<uint4*>(&Ls[row * 136 + 8 * c8]) =
        *reinterpret_cast<const uint4*>(V + (size_t)(kv0 + row) * 1536 + h * 128 + 8 * c8);
  }
  __syncthreads();
#pragma unroll
  for (int i = 0; i < 4; ++i) {
    const int c = tid + 256 * i;
    const int d = c >> 3, kc = c & 7;
    u16 tmp[8];
#pragma unroll
    for (int j = 0; j < 8; ++j) tmp[j] = Ls[(8 * kc + j) * 136 + d];
    *reinterpret_cast<uint4*>(Vt + ((size_t)h * 128 + d) * kvLen + kv0 + 8 * kc) =
        *reinterpret_cast<const uint4*>(tmp);
  }
}

// =====================================================================
// Fused dual flash attention, SINGLE-buffer staging (round-4 verified
// pattern: sync -> DMA -> sync -> compute). Round-5 post-mortem: the
// 2x-LDS double-buffer cost 3->2 blocks/CU (occupancy 29->12%) and
// regressed 1.7x; at 3 blocks/CU the wave-level overlap (m114) is the
// latency-hiding mechanism — keep LDS at 42.5 KB.
//   Phase 0: Q=Qc (prescaled), K/V = ref (kv=1024) -> Ox regs
//   Phase 1: Q=Qm (roped), K/V = main (kv=4096); out = Omain + Ox -> bf16 Ob
// Swizzles / fragment mappings identical to verified rounds 2-5.
// =====================================================================
__global__ __launch_bounds__(256) void flash2_kernel(
    const u16* __restrict__ Qc, const u16* __restrict__ Kc, const u16* __restrict__ Vtc,
    const u16* __restrict__ Qm, const u16* __restrict__ Km, const u16* __restrict__ Vtm,
    u16* __restrict__ Ob) {
  __shared__ u16 Ks[64 * 128];
  __shared__ u16 Vs[128 * 64];
  __shared__ u16 Pb[4][16 * 72];
  __shared__ float ab[4][16];

  const int tid = threadIdx.x;
  const int lane = tid & 63;
  const int w = tid >> 6;
  const int r = lane & 15;
  const int quad = lane >> 4;
  const int h = blockIdx.y;
  const int q0 = blockIdx.x * 64;
  const int qrow = q0 + 16 * w + r;
  const int sw = r & 7;

  f32x4 Ox[8];
#pragma unroll
  for (int dt = 0; dt < 8; ++dt) Ox[dt] = (f32x4){0.f, 0.f, 0.f, 0.f};

  for (int ph = 0; ph < 2; ++ph) {
    const u16* Q  = ph ? Qm : Qc;
    const u16* K  = ph ? Km : Kc;
    const u16* Vt = ph ? Vtm : Vtc;
    const int kvLen = ph ? 4096 : 1024;
    const int nt = kvLen >> 6;

    // Q fragments (B-operand of S^T): lane holds Q[qrow][32ks+8quad+j]
    short8 qf[4];
    {
      const u16* qbase = Q + (size_t)qrow * 1536 + h * 128 + 8 * quad;
#pragma unroll
      for (int ks = 0; ks < 4; ++ks)
        qf[ks] = *reinterpret_cast<const short8*>(qbase + 32 * ks);
    }

    // staging pointers (swizzle folded into global lane order)
    const u16* Vth = Vt + (size_t)h * 128 * kvLen;
    const u16* kg[4]; const u16* vg[4];
    u16* kl[4]; u16* vl[4];
    {
      const int p16 = lane & 15, rin = lane >> 4;
      const int p8 = lane & 7, din = lane >> 3;
#pragma unroll
      for (int j = 0; j < 4; ++j) {
        const int row = 16 * w + 4 * j + rin;
        kg[j] = K + (size_t)row * 1536 + h * 128 + 8 * (p16 ^ (row & 15));
        kl[j] = &Ks[(16 * w + 4 * j) * 128];
        const int d = 32 * w + 8 * j + din;
        vg[j] = Vth + (size_t)d * kvLen + 8 * (p8 ^ (d & 7));
        vl[j] = &Vs[(32 * w + 8 * j) * 64];
      }
    }

    f32x4 Oc[8];
#pragma unroll
    for (int dt = 0; dt < 8; ++dt) Oc[dt] = (f32x4){0.f, 0.f, 0.f, 0.f};
    float m_i = -1e30f, l_i = 0.f;

    for (int t = 0; t < nt; ++t) {
      __syncthreads();  // prior tile reads (or prior phase) done
      {
        const size_t ko = (size_t)t * 64 * 1536;
        const int vo = t * 64;
#pragma unroll
        for (int j = 0; j < 4; ++j) async16(kg[j] + ko, kl[j]);
#pragma unroll
        for (int j = 0; j < 4; ++j) async16(vg[j] + vo, vl[j]);
      }
      __syncthreads();  // DMA complete

      // S^T = K * Q^T (log2-domain; Q pre-scaled)
      f32x4 St[4];
#pragma unroll
      for (int mt = 0; mt < 4; ++mt) St[mt] = (f32x4){0.f, 0.f, 0.f, 0.f};
#pragma unroll
      for (int mt = 0; mt < 4; ++mt) {
        const u16* kp = &Ks[(16 * mt + r) * 128];
#pragma unroll
        for (int ks = 0; ks < 4; ++ks) {
          const short8 af = *reinterpret_cast<const short8*>(kp + 8 * ((quad + 4 * ks) ^ r));
          St[mt] = __builtin_amdgcn_mfma_f32_16x16x32_bf16(af, qf[ks], St[mt], 0, 0, 0);
        }
      }

      // online softmax (base 2); lane owns q-row r
      float mloc = -1e30f;
#pragma unroll
      for (int mt = 0; mt < 4; ++mt)
#pragma unroll
        for (int rr = 0; rr < 4; ++rr) mloc = fmaxf(mloc, St[mt][rr]);
      mloc = fmaxf(mloc, __shfl_xor(mloc, 16, 64));
      mloc = fmaxf(mloc, __shfl_xor(mloc, 32, 64));
      const float mn = fmaxf(m_i, mloc);

      float alpha = 1.0f;
      if (__any(mloc > m_i)) {
        alpha = fexp2(m_i - mn);
        if (quad == 0) ab[w][r] = alpha;
        const float4 a4 = *reinterpret_cast<const float4*>(&ab[w][4 * quad]);
#pragma unroll
        for (int dt = 0; dt < 8; ++dt) {
          Oc[dt][0] *= a4.x; Oc[dt][1] *= a4.y; Oc[dt][2] *= a4.z; Oc[dt][3] *= a4.w;
        }
      }

      float psum = 0.f;
      uint2 pk[4];
#pragma unroll
      for (int mt = 0; mt < 4; ++mt) {
        const float p0 = fexp2(St[mt][0] - mn);
        const float p1 = fexp2(St[mt][1] - mn);
        const float p2 = fexp2(St[mt][2] - mn);
        const float p3 = fexp2(St[mt][3] - mn);
        psum += (p0 + p1) + (p2 + p3);
        pk[mt].x = pack_bf16_rn(p0, p1);
        pk[mt].y = pack_bf16_rn(p2, p3);
      }
      psum += __shfl_xor(psum, 16, 64);
      psum += __shfl_xor(psum, 32, 64);
      l_i = l_i * alpha + psum;
      m_i = mn;

      // P -> wave-private LDS (A-operand layout [q=r][kpos])
#pragma unroll
      for (int mt = 0; mt < 4; ++mt)
        *reinterpret_cast<uint2*>(&Pb[w][r * 72 + 16 * mt + 4 * quad]) = pk[mt];

      const short8 pa0 = *reinterpret_cast<const short8*>(&Pb[w][r * 72 + 8 * quad]);
      const short8 pa1 = *reinterpret_cast<const short8*>(&Pb[w][r * 72 + 32 + 8 * quad]);

      // O += P * V
#pragma unroll
      for (int dt = 0; dt < 8; ++dt) {
        const int d = 16 * dt + r;
        const short8 b0 = *reinterpret_cast<const short8*>(&Vs[d * 64 + 8 * (quad ^ sw)]);
        const short8 b1 = *reinterpret_cast<const short8*>(&Vs[d * 64 + 8 * ((4 + quad) ^ sw)]);
        Oc[dt] = __builtin_amdgcn_mfma_f32_16x16x32_bf16(pa0, b0, Oc[dt], 0, 0, 0);
        Oc[dt] = __builtin_amdgcn_mfma_f32_16x16x32_bf16(pa1, b1, Oc[dt], 0, 0, 0);
      }
    }

    // phase finalize: normalize by 1/l (LDS broadcast, wave-private)
    if (quad == 0) ab[w][r] = 1.0f / l_i;
    const float4 li4 = *reinterpret_cast<const float4*>(&ab[w][4 * quad]);
    const float lv[4] = {li4.x, li4.y, li4.z, li4.w};
    if (ph == 0) {
#pragma unroll
      for (int dt = 0; dt < 8; ++dt)
#pragma unroll
        for (int rr = 0; rr < 4; ++rr) Ox[dt][rr] = Oc[dt][rr] * lv[rr];
    } else {
      u16* obb = Ob + (size_t)(q0 + 16 * w) * 1536 + h * 128;
#pragma unroll
      for (int rr = 0; rr < 4; ++rr) {
        u16* brow = obb + (size_t)(4 * quad + rr) * 1536 + r;
#pragma unroll
        for (int dt = 0; dt < 8; ++dt)
          brow[16 * dt] = f2b(Oc[dt][rr] * lv[rr] + Ox[dt][rr]);
      }
    }
  }
}

// =====================================================================
// Host orchestration (8 dispatches)
// =====================================================================
extern "C" void kernel_launch(void* const* d_in, const int* in_sizes, int n_in,
                              void* d_out, int out_size, void* d_ws, size_t ws_size,
                              hipStream_t stream) {
  (void)in_sizes; (void)n_in; (void)out_size; (void)ws_size;
  constexpr int T = 4096, TR = 1024, DIM = 1536, NH = 12;

  const float* hs  = (const float*)d_in[0];
  const float* rhs = (const float*)d_in[1];
  const float* rc  = (const float*)d_in[2];
  const float* rs  = (const float*)d_in[3];
  const float* Wq  = (const float*)d_in[4];
  const float* bq  = (const float*)d_in[5];
  const float* Wk  = (const float*)d_in[6];
  const float* bk  = (const float*)d_in[7];
  const float* Wv  = (const float*)d_in[8];
  const float* bv  = (const float*)d_in[9];
  const float* Wkr = (const float*)d_in[10];
  const float* bkr = (const float*)d_in[11];
  const float* Wvr = (const float*)d_in[12];
  const float* bvr = (const float*)d_in[13];
  const float* Wo  = (const float*)d_in[14];
  const float* bo  = (const float*)d_in[15];
  const float* gq  = (const float*)d_in[16];
  const float* gk  = (const float*)d_in[17];
  float* out = (float*)d_out;

  char* ws = (char*)d_ws;
  size_t off = 0;
  auto alloc = [&](size_t bytes) -> void* {
    void* p = ws + off;
    off += (bytes + 255) & ~(size_t)255;
    return p;
  };
  u16* bQ    = (u16*)alloc((size_t)T * DIM * 2);
  u16* bQr   = (u16*)alloc((size_t)T * DIM * 2);
  u16* bK    = (u16*)alloc((size_t)T * DIM * 2);
  u16* bV    = (u16*)alloc((size_t)T * DIM * 2);
  u16* bKr   = (u16*)alloc((size_t)TR * DIM * 2);
  u16* bVr   = (u16*)alloc((size_t)TR * DIM * 2);
  u16* bHs   = (u16*)alloc((size_t)T * DIM * 2);       // bf16 hs; ALIAS-> VtG
  u16* bRhs  = (u16*)alloc((size_t)TR * DIM * 2);      // bf16 rhs; ALIAS-> VtR
  u16* bWqkv = (u16*)alloc((size_t)3 * DIM * DIM * 2); // WqT|WkT|WvT; ALIAS-> bOb
  u16* bWr   = (u16*)alloc((size_t)2 * DIM * DIM * 2); // WkrT|WvrT
  u16* bWoT  = (u16*)alloc((size_t)DIM * DIM * 2);     // WoT (own slab)
  u16* VtG = bHs;
  u16* VtR = bRhs;
  u16* bOb = bWqkv;

  const dim3 blk(256);

  // 1. f32->bf16 converts (merged)
  conv2_kernel<<<dim3((T * DIM / 8 + TR * DIM / 8 + 255) / 256), blk, 0, stream>>>(
      hs, bHs, T * DIM / 8, rhs, bRhs, TR * DIM / 8);

  // 2. weight transpose-converts (all six merged)
  transconv6_kernel<<<dim3(24, 24, 6), blk, 0, stream>>>(
      Wq, Wk, Wv, Wkr, Wvr, Wo,
      bWqkv + 0 * (size_t)DIM * DIM, bWqkv + 1 * (size_t)DIM * DIM,
      bWqkv + 2 * (size_t)DIM * DIM, bWr + 0 * (size_t)DIM * DIM,
      bWr + 1 * (size_t)DIM * DIM, bWoT);

  // 3-4. projections (QKV fused 128-tile; KrVr 64-tile for occupancy)
  gemm128_kernel<4, u16><<<dim3(36, 32), blk, 0, stream>>>(
      bHs, DIM, bWqkv, DIM, bQ, bK, bV, DIM, bq, bk, bv, DIM);
  gemm128_kernel<2, u16><<<dim3(24, 16), blk, 0, stream>>>(
      bRhs, DIM, bWr, DIM, bKr, bVr, (u16*)nullptr, DIM, bkr, bvr, nullptr, DIM);

  // 5. rmsnorm/rope (merged; q-path pre-scaled by QS)
  rmsnorm3_kernel<<<dim3(T, 3), blk, 0, stream>>>(
      bQ, bK, bKr, gq, gk, rc, rs, bQ, bQr, bK, bKr);

  // 6. per-head V transposes (merged; alias buffers are dead)
  vtrans2_kernel<<<dim3(T / 64, NH, 2), blk, 0, stream>>>(bV, VtG, bVr, VtR);

  // 7. fused dual flash attention -> bf16 bOb
  flash2_kernel<<<dim3(T / 64, NH), blk, 0, stream>>>(
      bQ, bKr, VtR, bQr, bK, VtG, bOb);

  // 8. output projection (64-row tiles for occupancy)
  gemm128_kernel<2, float><<<dim3(12, 64), blk, 0, stream>>>(
      bOb, DIM, bWoT, DIM, out, (float*)nullptr, (float*)nullptr, DIM, bo, nullptr, nullptr, DIM);
}

// Round 7
// 546.672 us; speedup vs baseline: 1.3203x; 1.1057x over previous
//
#include <hip/hip_runtime.h>

typedef unsigned short u16;
typedef unsigned int u32;
typedef __attribute__((ext_vector_type(8))) short short8;
typedef __attribute__((ext_vector_type(4))) float f32x4;

// ---------- bf16 helpers ----------
__device__ inline u16 f2b(float f) {  // RNE
  u32 u = __builtin_bit_cast(u32, f);
  u += 0x7fff + ((u >> 16) & 1);
  return (u16)(u >> 16);
}
__device__ inline float b2f(u16 u) {
  return __builtin_bit_cast(float, (u32)u << 16);
}
// round-to-nearest (ties away) pack — cheaper than RNE, used for P only
__device__ inline u32 pack_bf16_rn(float a, float b) {
  const u32 ua = __builtin_bit_cast(u32, a) + 0x8000u;
  const u32 ub = __builtin_bit_cast(u32, b) + 0x8000u;
  return (ua >> 16) | (ub & 0xffff0000u);
}
__device__ inline void c_store(float* p, float v) { *p = v; }
__device__ inline void c_store(u16* p, float v) { *p = f2b(v); }

__device__ inline float fexp2(float x) {
#if __has_builtin(__builtin_amdgcn_exp2f)
  return __builtin_amdgcn_exp2f(x);
#else
  return exp2f(x);
#endif
}

// ---------- async global->LDS, 16B per lane ----------
typedef const __attribute__((address_space(1))) u32 gu32;
typedef __attribute__((address_space(3))) u32 lu32;
__device__ inline void async16(const u16* g, u16* l) {
  __builtin_amdgcn_global_load_lds((gu32*)g, (lu32*)l, 16, 0, 0);
}

// Q scale folded into rmsnorm producer: 1/sqrt(128) * log2(e)
#define QS (0.08838834764831843f * 1.4426950408889634f)

// =====================================================================
// (32*MI)x128x(K,BK=32) bf16 GEMM, m97 structure (verified r3-r6).
// MI=4: 128-row tile. MI=2: 64-row tile for occupancy-starved shapes.
// =====================================================================
template <int MI, typename TC>
__global__ __launch_bounds__(256) void gemm128_kernel(
    const u16* __restrict__ A, long lda,
    const u16* __restrict__ Bt, long ldb,
    TC* __restrict__ C0, TC* __restrict__ C1, TC* __restrict__ C2, long ldc,
    const float* b0, const float* b1, const float* b2,
    int K) {
  __shared__ u16 As[32 * MI * 32];
  __shared__ u16 Bs[128 * 32];

  const int tid = threadIdx.x;
  const int lane = tid & 63;
  const int w = tid >> 6;
  const int r = lane & 15;
  const int quad = lane >> 4;
  const int m0 = blockIdx.y * (32 * MI);
  const int nb = blockIdx.x * 128;
  const int seg = nb / 1536;
  const int nc = nb - seg * 1536;
  TC* C = seg == 0 ? C0 : (seg == 1 ? C1 : C2);
  const float* bias = seg == 0 ? b0 : (seg == 1 ? b1 : b2);

  const int srow = lane >> 2;
  const int sx = ((lane & 3) ^ (srow & 3)) * 8;
  const u16* Ag = A + (size_t)(m0 + w * 8 * MI + srow) * lda + sx;
  const u16* Bg = Bt + (size_t)(nb + w * 32 + srow) * ldb + sx;
  u16* Al[MI / 2];
#pragma unroll
  for (int j = 0; j < MI / 2; ++j) Al[j] = &As[(w * 8 * MI + 16 * j) * 32];
  u16* const Bl0 = &Bs[(w * 32) * 32];
  u16* const Bl1 = &Bs[(w * 32 + 16) * 32];

  const int wm = (w >> 1) * (16 * MI);
  const int wn = (w & 1) * 64;

  f32x4 acc[MI][4];
#pragma unroll
  for (int i = 0; i < MI; ++i)
#pragma unroll
    for (int j = 0; j < 4; ++j) acc[i][j] = (f32x4){0.f, 0.f, 0.f, 0.f};

  const int fco = (quad ^ (r & 3)) * 8;

  for (int kk = 0; kk < K; kk += 32) {
    __syncthreads();
#pragma unroll
    for (int j = 0; j < MI / 2; ++j) async16(Ag + kk + (size_t)(16 * j) * lda, Al[j]);
    async16(Bg + kk, Bl0);
    async16(Bg + kk + 16 * ldb, Bl1);
    __syncthreads();

    short8 af[MI], bf[4];
#pragma unroll
    for (int mi = 0; mi < MI; ++mi)
      af[mi] = *reinterpret_cast<const short8*>(&As[(wm + 16 * mi + r) * 32 + fco]);
#pragma unroll
    for (int ni = 0; ni < 4; ++ni)
      bf[ni] = *reinterpret_cast<const short8*>(&Bs[(wn + 16 * ni + r) * 32 + fco]);
#pragma unroll
    for (int mi = 0; mi < MI; ++mi)
#pragma unroll
      for (int ni = 0; ni < 4; ++ni)
        acc[mi][ni] = __builtin_amdgcn_mfma_f32_16x16x32_bf16(af[mi], bf[ni], acc[mi][ni], 0, 0, 0);
  }

#pragma unroll
  for (int mi = 0; mi < MI; ++mi)
#pragma unroll
    for (int ni = 0; ni < 4; ++ni)
#pragma unroll
      for (int rr = 0; rr < 4; ++rr) {
        const int row = m0 + wm + 16 * mi + 4 * quad + rr;
        const int col = nc + wn + 16 * ni + r;
        c_store(&C[(size_t)row * ldc + col], acc[mi][ni][rr] + bias[col]);
      }
}

// =====================================================================
// Merged f32->bf16 convert for hs and rhs
// =====================================================================
__global__ __launch_bounds__(256) void conv2_kernel(
    const float* __restrict__ xa, u16* __restrict__ ya, int n8a,
    const float* __restrict__ xb, u16* __restrict__ yb, int n8b) {
  int i = blockIdx.x * 256 + threadIdx.x;
  const float* x;
  u16* y;
  if (i < n8a) {
    x = xa; y = ya;
  } else {
    i -= n8a;
    if (i >= n8b) return;
    x = xb; y = yb;
  }
  const float4 v0 = reinterpret_cast<const float4*>(x)[2 * i];
  const float4 v1 = reinterpret_cast<const float4*>(x)[2 * i + 1];
  uint4 rv;
  rv.x = (u32)f2b(v0.x) | ((u32)f2b(v0.y) << 16);
  rv.y = (u32)f2b(v0.z) | ((u32)f2b(v0.w) << 16);
  rv.z = (u32)f2b(v1.x) | ((u32)f2b(v1.y) << 16);
  rv.w = (u32)f2b(v1.z) | ((u32)f2b(v1.w) << 16);
  reinterpret_cast<uint4*>(y)[i] = rv;
}

// =====================================================================
// Transpose-convert, all 6 weights merged (W f32 [1536][1536] -> Wt^T bf16)
// =====================================================================
__device__ inline void transconv_body(const float* __restrict__ W, u16* __restrict__ Wt) {
  __shared__ u16 Ls[64 * 72];
  const int tid = threadIdx.x;
  const int k0 = blockIdx.y * 64;
  const int n0 = blockIdx.x * 64;
#pragma unroll
  for (int i = 0; i < 4; ++i) {
    const int c = tid + 256 * i;
    const int row = c >> 4;
    const int c4 = (c & 15) * 4;
    const float4 v = *reinterpret_cast<const float4*>(&W[(size_t)(k0 + row) * 1536 + n0 + c4]);
    Ls[(c4 + 0) * 72 + row] = f2b(v.x);
    Ls[(c4 + 1) * 72 + row] = f2b(v.y);
    Ls[(c4 + 2) * 72 + row] = f2b(v.z);
    Ls[(c4 + 3) * 72 + row] = f2b(v.w);
  }
  __syncthreads();
#pragma unroll
  for (int i = 0; i < 2; ++i) {
    const int c = tid + 256 * i;
    const int n = c >> 3;
    const int kc = (c & 7) * 8;
    u16 tmp[8];
#pragma unroll
    for (int j = 0; j < 8; ++j) tmp[j] = Ls[n * 72 + kc + j];
    *reinterpret_cast<uint4*>(&Wt[(size_t)(n0 + n) * 1536 + k0 + kc]) =
        *reinterpret_cast<const uint4*>(tmp);
  }
}

__global__ __launch_bounds__(256) void transconv6_kernel(
    const float* W0, const float* W1, const float* W2,
    const float* W3, const float* W4, const float* W5,
    u16* T0, u16* T1, u16* T2, u16* T3, u16* T4, u16* T5) {
  const int z = blockIdx.z;
  const float* W = z == 0 ? W0 : z == 1 ? W1 : z == 2 ? W2 : z == 3 ? W3 : z == 4 ? W4 : W5;
  u16* Wt = z == 0 ? T0 : z == 1 ? T1 : z == 2 ? T2 : z == 3 ? T3 : z == 4 ? T4 : T5;
  transconv_body(W, Wt);
}

// =====================================================================
// Merged RMSNorm: z=0 q-path (scaled by QS, plain+rope), z=1 k-path
// (rope), z=2 ref-k (1024 rows, plain). Verified r4-r6.
// =====================================================================
__global__ __launch_bounds__(256) void rmsnorm3_kernel(
    const u16* xq, const u16* xk, const u16* xkr,
    const float* gq, const float* gk,
    const float* rc, const float* rs,
    u16* oq_plain, u16* oq_rope, u16* ok_rope, u16* okr_plain) {
  __shared__ float red[4];
  const int z = blockIdx.y;
  const int row = blockIdx.x;
  if (z == 2 && row >= 1024) return;
  const u16* x; const float* g; u16* po; u16* pr; float sc;
  if (z == 0)      { x = xq;  g = gq; po = oq_plain; pr = oq_rope; sc = QS;  }
  else if (z == 1) { x = xk;  g = gk; po = nullptr;  pr = ok_rope; sc = 1.f; }
  else             { x = xkr; g = gk; po = okr_plain; pr = nullptr; sc = 1.f; }

  const int tid = threadIdx.x;
  const u32* xr = reinterpret_cast<const u32*>(x + (size_t)row * 1536);
  float xe[3], xo[3];
  float ss = 0.f;
#pragma unroll
  for (int j = 0; j < 3; ++j) {
    const u32 u = xr[tid + 256 * j];
    const float e = b2f((u16)(u & 0xffff));
    const float o = b2f((u16)(u >> 16));
    xe[j] = e; xo[j] = o;
    ss += e * e + o * o;
  }
#pragma unroll
  for (int off = 32; off; off >>= 1) ss += __shfl_xor(ss, off, 64);
  if ((tid & 63) == 0) red[tid >> 6] = ss;
  __syncthreads();
  const float total = red[0] + red[1] + red[2] + red[3];
  const float rinv = rsqrtf(total * (1.0f / 1536.0f) + 1e-6f) * sc;
  u32* po32 = po ? reinterpret_cast<u32*>(po + (size_t)row * 1536) : nullptr;
  u32* pr32 = pr ? reinterpret_cast<u32*>(pr + (size_t)row * 1536) : nullptr;
#pragma unroll
  for (int j = 0; j < 3; ++j) {
    const int p = tid + 256 * j;
    const float2 gg = reinterpret_cast<const float2*>(g)[p];
    const float e = xe[j] * rinv * gg.x;
    const float o = xo[j] * rinv * gg.y;
    if (po32) po32[p] = (u32)f2b(e) | ((u32)f2b(o) << 16);
    if (pr32) {
      const int i = p & 63;
      const float c = rc[row * 64 + i];
      const float s = rs[row * 64 + i];
      const float re = e * c - o * s;
      const float im = e * s + o * c;
      pr32[p] = (u32)f2b(re) | ((u32)f2b(im) << 16);
    }
  }
}

// =====================================================================
// Merged per-head V transpose (verified r4-r6)
// =====================================================================
__global__ __launch_bounds__(256) void vtrans2_kernel(
    const u16* __restrict__ V0, u16* __restrict__ Vt0,
    const u16* __restrict__ V1, u16* __restrict__ Vt1) {
  __shared__ u16 Ls[64 * 136];
  const int z = blockIdx.z;
  const int kvLen = z == 0 ? 4096 : 1024;
  const int kv0 = blockIdx.x * 64;
  if (kv0 >= kvLen) return;
  const u16* V = z == 0 ? V0 : V1;
  u16* Vt = z == 0 ? Vt0 : Vt1;
  const int tid = threadIdx.x;
  const int h = blockIdx.y;
#pragma unroll
  for (int i = 0; i < 4; ++i) {
    const int c = tid + 256 * i;
    const int row = c >> 4, c8 = c & 15;
    *reinterpret_cast<uint4*>(&Ls[row * 136 + 8 * c8]) =
        *reinterpret_cast<const uint4*>(V + (size_t)(kv0 + row) * 1536 + h * 128 + 8 * c8);
  }
  __syncthreads();
#pragma unroll
  for (int i = 0; i < 4; ++i) {
    const int c = tid + 256 * i;
    const int d = c >> 3, kc = c & 7;
    u16 tmp[8];
#pragma unroll
    for (int j = 0; j < 8; ++j) tmp[j] = Ls[(8 * kc + j) * 136 + d];
    *reinterpret_cast<uint4*>(Vt + ((size_t)h * 128 + d) * kvLen + kv0 + 8 * kc) =
        *reinterpret_cast<const uint4*>(tmp);
  }
}

// =====================================================================
// Flash attention, r4-verified split structure, retuned for 4 blocks/CU:
//  - __launch_bounds__(256,4): cap total regs at 128 (4 waves/SIMD).
//    r6 post-mortem: registers, not LDS, were the occupancy binder.
//  - LDS 38.1 KB (< 40 KB = 4-block threshold): Pb stride 72 -> 40 by
//    running PV in two k-halves (kpos 0-31, 32-63) reusing the same Pb
//    region. Same-wave LDS ops are in-order -> write/read/overwrite safe.
//  - 32-bit staging offsets + uniform base (fewer pointer VGPRs).
// Swizzles / fragment mappings identical to verified rounds 2-6.
// =====================================================================
__global__ __launch_bounds__(256, 4) void flash_kernel(
    const u16* __restrict__ Q, const u16* __restrict__ K,
    const u16* __restrict__ Vt, float* __restrict__ O,
    u16* __restrict__ Ob, int kvLen, int addO) {
  __shared__ u16 Ks[64 * 128];
  __shared__ u16 Vs[128 * 64];
  __shared__ u16 Pb[4][16 * 40];
  __shared__ float ab[4][16];

  const int tid = threadIdx.x;
  const int lane = tid & 63;
  const int w = tid >> 6;
  const int r = lane & 15;
  const int quad = lane >> 4;
  const int h = blockIdx.y;
  const int q0 = blockIdx.x * 64;
  const int qrow = q0 + 16 * w + r;
  const int sw = r & 7;

  // Q fragments (B-operand of S^T): lane holds Q[qrow][32ks+8quad+j]
  short8 qf[4];
  {
    const u16* qbase = Q + (size_t)qrow * 1536 + h * 128 + 8 * quad;
#pragma unroll
    for (int ks = 0; ks < 4; ++ks)
      qf[ks] = *reinterpret_cast<const short8*>(qbase + 32 * ks);
  }

  // staging: uniform bases + 32-bit per-lane element offsets
  const u16* Kb = K + h * 128;
  const u16* Vb = Vt + (size_t)h * 128 * kvLen;
  u32 koff[4], voff[4];
  int klo[4], vlo[4];
  {
    const int p16 = lane & 15, rin = lane >> 4;
    const int p8 = lane & 7, din = lane >> 3;
#pragma unroll
    for (int j = 0; j < 4; ++j) {
      const int row = 16 * w + 4 * j + rin;
      koff[j] = (u32)row * 1536u + 8u * (u32)(p16 ^ (row & 15));
      klo[j] = (16 * w + 4 * j) * 128;
      const int d = 32 * w + 8 * j + din;
      voff[j] = (u32)d * (u32)kvLen + 8u * (u32)(p8 ^ (d & 7));
      vlo[j] = (32 * w + 8 * j) * 64;
    }
  }

  f32x4 Oc[8];
#pragma unroll
  for (int dt = 0; dt < 8; ++dt) Oc[dt] = (f32x4){0.f, 0.f, 0.f, 0.f};
  float m_i = -1e30f, l_i = 0.f;

  const int nt = kvLen >> 6;
  for (int t = 0; t < nt; ++t) {
    __syncthreads();  // prior tile reads done
    {
      const size_t ko = (size_t)t * (64 * 1536);
      const size_t vo = (size_t)t * 64;
#pragma unroll
      for (int j = 0; j < 4; ++j) async16(Kb + ko + koff[j], &Ks[klo[j]]);
#pragma unroll
      for (int j = 0; j < 4; ++j) async16(Vb + vo + voff[j], &Vs[vlo[j]]);
    }
    __syncthreads();  // DMA complete

    // S^T = K * Q^T (log2-domain; Q pre-scaled)
    f32x4 St[4];
#pragma unroll
    for (int mt = 0; mt < 4; ++mt) St[mt] = (f32x4){0.f, 0.f, 0.f, 0.f};
#pragma unroll
    for (int mt = 0; mt < 4; ++mt) {
      const u16* kp = &Ks[(16 * mt + r) * 128];
#pragma unroll
      for (int ks = 0; ks < 4; ++ks) {
        const short8 af = *reinterpret_cast<const short8*>(kp + 8 * ((quad + 4 * ks) ^ r));
        St[mt] = __builtin_amdgcn_mfma_f32_16x16x32_bf16(af, qf[ks], St[mt], 0, 0, 0);
      }
    }

    // online softmax (base 2); lane owns q-row r
    float mloc = -1e30f;
#pragma unroll
    for (int mt = 0; mt < 4; ++mt)
#pragma unroll
      for (int rr = 0; rr < 4; ++rr) mloc = fmaxf(mloc, St[mt][rr]);
    mloc = fmaxf(mloc, __shfl_xor(mloc, 16, 64));
    mloc = fmaxf(mloc, __shfl_xor(mloc, 32, 64));
    const float mn = fmaxf(m_i, mloc);

    float alpha = 1.0f;
    if (__any(mloc > m_i)) {
      alpha = fexp2(m_i - mn);
      if (quad == 0) ab[w][r] = alpha;
      const float4 a4 = *reinterpret_cast<const float4*>(&ab[w][4 * quad]);
#pragma unroll
      for (int dt = 0; dt < 8; ++dt) {
        Oc[dt][0] *= a4.x; Oc[dt][1] *= a4.y; Oc[dt][2] *= a4.z; Oc[dt][3] *= a4.w;
      }
    }

    float psum = 0.f;
    uint2 pk[4];
#pragma unroll
    for (int mt = 0; mt < 4; ++mt) {
      const float p0 = fexp2(St[mt][0] - mn);
      const float p1 = fexp2(St[mt][1] - mn);
      const float p2 = fexp2(St[mt][2] - mn);
      const float p3 = fexp2(St[mt][3] - mn);
      psum += (p0 + p1) + (p2 + p3);
      pk[mt].x = pack_bf16_rn(p0, p1);
      pk[mt].y = pack_bf16_rn(p2, p3);
    }
    psum += __shfl_xor(psum, 16, 64);
    psum += __shfl_xor(psum, 32, 64);
    l_i = l_i * alpha + psum;
    m_i = mn;

    // PV in two k-halves, reusing the 16x40 wave-private Pb region.
    // half A: kpos 0..31
#pragma unroll
    for (int mt = 0; mt < 2; ++mt)
      *reinterpret_cast<uint2*>(&Pb[w][r * 40 + 16 * mt + 4 * quad]) = pk[mt];
    {
      const short8 pa0 = *reinterpret_cast<const short8*>(&Pb[w][r * 40 + 8 * quad]);
#pragma unroll
      for (int dt = 0; dt < 8; ++dt) {
        const int d = 16 * dt + r;
        const short8 b0 = *reinterpret_cast<const short8*>(&Vs[d * 64 + 8 * (quad ^ sw)]);
        Oc[dt] = __builtin_amdgcn_mfma_f32_16x16x32_bf16(pa0, b0, Oc[dt], 0, 0, 0);
      }
    }
    // half B: kpos 32..63 (same-wave LDS in-order: safe overwrite)
#pragma unroll
    for (int mt = 2; mt < 4; ++mt)
      *reinterpret_cast<uint2*>(&Pb[w][r * 40 + 16 * (mt - 2) + 4 * quad]) = pk[mt];
    {
      const short8 pa1 = *reinterpret_cast<const short8*>(&Pb[w][r * 40 + 8 * quad]);
#pragma unroll
      for (int dt = 0; dt < 8; ++dt) {
        const int d = 16 * dt + r;
        const short8 b1 = *reinterpret_cast<const short8*>(&Vs[d * 64 + 8 * ((4 + quad) ^ sw)]);
        Oc[dt] = __builtin_amdgcn_mfma_f32_16x16x32_bf16(pa1, b1, Oc[dt], 0, 0, 0);
      }
    }
  }

  // normalize by 1/l (LDS broadcast, wave-private) and store
  if (quad == 0) ab[w][r] = 1.0f / l_i;
  const float4 li4 = *reinterpret_cast<const float4*>(&ab[w][4 * quad]);
  const float lv[4] = {li4.x, li4.y, li4.z, li4.w};
  float* obf = O + (size_t)(q0 + 16 * w) * 1536 + h * 128;
  u16* obb = Ob + (size_t)(q0 + 16 * w) * 1536 + h * 128;
#pragma unroll
  for (int rr = 0; rr < 4; ++rr) {
    float* orow = obf + (size_t)(4 * quad + rr) * 1536 + r;
    u16* brow = obb + (size_t)(4 * quad + rr) * 1536 + r;
#pragma unroll
    for (int dt = 0; dt < 8; ++dt) {
      float v = Oc[dt][rr] * lv[rr];
      if (addO) {
        v += orow[16 * dt];
        brow[16 * dt] = f2b(v);
      } else {
        orow[16 * dt] = v;
      }
    }
  }
}

// =====================================================================
// Host orchestration (9 dispatches)
// =====================================================================
extern "C" void kernel_launch(void* const* d_in, const int* in_sizes, int n_in,
                              void* d_out, int out_size, void* d_ws, size_t ws_size,
                              hipStream_t stream) {
  (void)in_sizes; (void)n_in; (void)out_size; (void)ws_size;
  constexpr int T = 4096, TR = 1024, DIM = 1536, NH = 12;

  const float* hs  = (const float*)d_in[0];
  const float* rhs = (const float*)d_in[1];
  const float* rc  = (const float*)d_in[2];
  const float* rs  = (const float*)d_in[3];
  const float* Wq  = (const float*)d_in[4];
  const float* bq  = (const float*)d_in[5];
  const float* Wk  = (const float*)d_in[6];
  const float* bk  = (const float*)d_in[7];
  const float* Wv  = (const float*)d_in[8];
  const float* bv  = (const float*)d_in[9];
  const float* Wkr = (const float*)d_in[10];
  const float* bkr = (const float*)d_in[11];
  const float* Wvr = (const float*)d_in[12];
  const float* bvr = (const float*)d_in[13];
  const float* Wo  = (const float*)d_in[14];
  const float* bo  = (const float*)d_in[15];
  const float* gq  = (const float*)d_in[16];
  const float* gk  = (const float*)d_in[17];
  float* out = (float*)d_out;

  char* ws = (char*)d_ws;
  size_t off = 0;
  auto alloc = [&](size_t bytes) -> void* {
    void* p = ws + off;
    off += (bytes + 255) & ~(size_t)255;
    return p;
  };
  u16* bQ    = (u16*)alloc((size_t)T * DIM * 2);
  u16* bQr   = (u16*)alloc((size_t)T * DIM * 2);
  u16* bK    = (u16*)alloc((size_t)T * DIM * 2);
  u16* bV    = (u16*)alloc((size_t)T * DIM * 2);
  u16* bKr   = (u16*)alloc((size_t)TR * DIM * 2);
  u16* bVr   = (u16*)alloc((size_t)TR * DIM * 2);
  float* bO  = (float*)alloc((size_t)T * DIM * 4);     // cross-attn out (f32)
  u16* bHs   = (u16*)alloc((size_t)T * DIM * 2);       // bf16 hs; ALIAS-> VtG
  u16* bRhs  = (u16*)alloc((size_t)TR * DIM * 2);      // bf16 rhs; ALIAS-> VtR
  u16* bWqkv = (u16*)alloc((size_t)3 * DIM * DIM * 2); // WqT|WkT|WvT; ALIAS-> bOb
  u16* bWr   = (u16*)alloc((size_t)2 * DIM * DIM * 2); // WkrT|WvrT
  u16* bWoT  = (u16*)alloc((size_t)DIM * DIM * 2);     // WoT (own slab)
  u16* VtG = bHs;
  u16* VtR = bRhs;
  u16* bOb = bWqkv;

  const dim3 blk(256);

  // 1. f32->bf16 converts (merged)
  conv2_kernel<<<dim3((T * DIM / 8 + TR * DIM / 8 + 255) / 256), blk, 0, stream>>>(
      hs, bHs, T * DIM / 8, rhs, bRhs, TR * DIM / 8);

  // 2. weight transpose-converts (all six merged)
  transconv6_kernel<<<dim3(24, 24, 6), blk, 0, stream>>>(
      Wq, Wk, Wv, Wkr, Wvr, Wo,
      bWqkv + 0 * (size_t)DIM * DIM, bWqkv + 1 * (size_t)DIM * DIM,
      bWqkv + 2 * (size_t)DIM * DIM, bWr + 0 * (size_t)DIM * DIM,
      bWr + 1 * (size_t)DIM * DIM, bWoT);

  // 3-4. projections (QKV fused 128-tile; KrVr 64-tile for occupancy)
  gemm128_kernel<4, u16><<<dim3(36, 32), blk, 0, stream>>>(
      bHs, DIM, bWqkv, DIM, bQ, bK, bV, DIM, bq, bk, bv, DIM);
  gemm128_kernel<2, u16><<<dim3(24, 16), blk, 0, stream>>>(
      bRhs, DIM, bWr, DIM, bKr, bVr, (u16*)nullptr, DIM, bkr, bvr, nullptr, DIM);

  // 5. rmsnorm/rope (merged; q-path pre-scaled by QS)
  rmsnorm3_kernel<<<dim3(T, 3), blk, 0, stream>>>(
      bQ, bK, bKr, gq, gk, rc, rs, bQ, bQr, bK, bKr);

  // 6. per-head V transposes (merged; alias buffers are dead)
  vtrans2_kernel<<<dim3(T / 64, NH, 2), blk, 0, stream>>>(bV, VtG, bVr, VtR);

  // 7-8. flash attention: cross writes f32 bO; main adds + writes bf16 bOb
  flash_kernel<<<dim3(T / 64, NH), blk, 0, stream>>>(bQ, bKr, VtR, bO, bOb, TR, 0);
  flash_kernel<<<dim3(T / 64, NH), blk, 0, stream>>>(bQr, bK, VtG, bO, bOb, T, 1);

  // 9. output projection (64-row tiles for occupancy)
  gemm128_kernel<2, float><<<dim3(12, 64), blk, 0, stream>>>(
      bOb, DIM, bWoT, DIM, out, (float*)nullptr, (float*)nullptr, DIM, bo, nullptr, nullptr, DIM);
}